// Round 10
// baseline (904.568 us; speedup 1.0000x reference)
//
#include <hip/hip_runtime.h>

#define N_NODES 100000
#define N_EDGES 1600000
#define SCAN_NBLK 98   // ceil(100000/1024)
#define SMAX 1024      // staged edges per block (16 nodes, mean 256)
#define GBLK 6250      // gather blocks per slice

typedef float4 f4;

__device__ __forceinline__ float bf2f(unsigned short v) {
  return __uint_as_float(((unsigned)v) << 16);
}
__device__ __forceinline__ unsigned short f2bf(float f) {
  unsigned u = __float_as_uint(f);
  u += 0x7FFF + ((u >> 16) & 1);   // round-to-nearest-even
  return (unsigned short)(u >> 16);
}
__device__ __forceinline__ float bfLO(unsigned u) { return __uint_as_float(u << 16); }
__device__ __forceinline__ float bfHI(unsigned u) { return __uint_as_float(u & 0xFFFF0000u); }

// ---------------- CSR build ----------------
__global__ __launch_bounds__(256) void k_count(const int* __restrict__ dst, int* __restrict__ counts) {
  int i = blockIdx.x * 256 + threadIdx.x;
  if (i < N_EDGES) atomicAdd(&counts[dst[i]], 1);
}

__global__ __launch_bounds__(256) void k_scan_a(const int* __restrict__ counts, int* __restrict__ blk) {
  __shared__ int red[256];
  const int t = threadIdx.x;
  const int base = blockIdx.x * 1024;
  int s = 0;
  #pragma unroll
  for (int i = 0; i < 4; ++i) {
    int idx = base + t + i * 256;
    if (idx < N_NODES) s += counts[idx];
  }
  red[t] = s; __syncthreads();
  for (int off = 128; off >= 1; off >>= 1) {
    if (t < off) red[t] += red[t + off];
    __syncthreads();
  }
  if (t == 0) blk[blockIdx.x] = red[0];
}

__global__ __launch_bounds__(128) void k_scan_b(int* __restrict__ blk) {
  __shared__ int v[128];
  const int t = threadIdx.x;
  int val = (t < SCAN_NBLK) ? blk[t] : 0;
  v[t] = val; __syncthreads();
  for (int off = 1; off < 128; off <<= 1) {
    int a = (t >= off) ? v[t - off] : 0;
    __syncthreads();
    v[t] += a;
    __syncthreads();
  }
  if (t < SCAN_NBLK) blk[t] = v[t] - val;  // exclusive
}

__global__ __launch_bounds__(256) void k_scan_c(const int* __restrict__ counts, const int* __restrict__ blkoff,
                                                int* __restrict__ rowptr, int* __restrict__ cursor,
                                                float* __restrict__ invd) {
  __shared__ int ps[256];
  const int t = threadIdx.x;
  const int base = blockIdx.x * 1024 + t * 4;
  int c[4]; int s = 0;
  #pragma unroll
  for (int i = 0; i < 4; ++i) {
    int idx = base + i;
    c[i] = (idx < N_NODES) ? counts[idx] : 0;
    s += c[i];
  }
  ps[t] = s; __syncthreads();
  for (int off = 1; off < 256; off <<= 1) {
    int a = (t >= off) ? ps[t - off] : 0;
    __syncthreads();
    ps[t] += a;
    __syncthreads();
  }
  int run = blkoff[blockIdx.x] + ps[t] - s;
  #pragma unroll
  for (int i = 0; i < 4; ++i) {
    int idx = base + i;
    if (idx < N_NODES) {
      rowptr[idx] = run;
      cursor[idx] = run;
      invd[idx] = 1.0f / fmaxf((float)c[i], 1.0f);
      run += c[i];
      if (idx == N_NODES - 1) rowptr[N_NODES] = run;
    }
  }
}

__global__ __launch_bounds__(256) void k_place(const int* __restrict__ src, const int* __restrict__ dst,
                                               int* __restrict__ cursor, int* __restrict__ srcs) {
  int e = blockIdx.x * 256 + threadIdx.x;
  if (e < N_EDGES) {
    int pos = atomicAdd(&cursor[dst[e]], 1);
    srcs[pos] = src[e];
  }
}

// ------------- combined projection weights for final layer -------------
__global__ void k_precomp(const float* __restrict__ Wl2, const float* __restrict__ Wr2,
                          const float* __restrict__ Wf, const float* __restrict__ bfv,
                          const float* __restrict__ b2,
                          float* __restrict__ Wcl, float* __restrict__ Wcr, float* __restrict__ bc) {
  int o = blockIdx.x, k = threadIdx.x;  // o<40, k<128
  float al = 0.f, ar = 0.f;
  for (int j = 0; j < 64; ++j) {
    float wl = Wl2[o*128 + 64 + j], wr = Wr2[o*128 + 64 + j];
    float wf = Wf[j*128 + k];
    al = fmaf(wl, wf, al); ar = fmaf(wr, wf, ar);
  }
  Wcl[o*128 + k] = al; Wcr[o*128 + k] = ar;
  if (k == 0) {
    float sl = 0.f, sr = 0.f;
    for (int j = 0; j < 64; ++j) { sl += Wl2[o*128+64+j]*bfv[j]; sr += Wr2[o*128+64+j]*bfv[j]; }
    bc[o] = sl; bc[40+o] = sr + b2[o];
  }
}

template<int K>
__global__ __launch_bounds__(256) void k_buildwt(const float* __restrict__ W1, const float* __restrict__ W2,
                                                 float* __restrict__ dst) {
  int idx = blockIdx.x * 256 + threadIdx.x;
  if (idx >= K*128) return;
  int c = idx & 127, k = idx >> 7;
  dst[idx] = (c < 64) ? W1[c*K + k] : W2[(c-64)*K + k];
}

__global__ __launch_bounds__(256) void k_buildwtf(const float* __restrict__ Wl2, const float* __restrict__ Wr2,
                                                  const float* __restrict__ Wcl, const float* __restrict__ Wcr,
                                                  float* __restrict__ dst) {
  int idx = blockIdx.x * 256 + threadIdx.x;
  if (idx >= 192*80) return;
  int c = idx % 80, k = idx / 80;
  float w;
  if (k < 64) w = (c < 40) ? Wl2[c*128 + k] : Wr2[(c-40)*128 + k];
  else        w = (c < 40) ? Wcl[c*128 + k-64] : Wcr[(c-40)*128 + k-64];
  dst[idx] = w;
}

// ------------- dual GEMM: out1(bf16, SLICE-MAJOR [4][N][16]) = in@W1.T, out2(f32) = in@W2.T + b2
template<int K, bool BN>
__global__ __launch_bounds__(256) void k_gemm_dual(
    const float* __restrict__ in, const float* __restrict__ stats,
    const float* __restrict__ g, const float* __restrict__ be,
    const float* __restrict__ wtg, const float* __restrict__ bias2,
    unsigned short* __restrict__ out1, float* __restrict__ out2) {
  __shared__ float wt[64*128];
  __shared__ float xs[32*K];
  __shared__ float ssl[128];
  const int tx = threadIdx.x;
  if (BN) {
    if (tx < 64) {
      float mean = stats[tx] * (1.0f / N_NODES);
      float var  = stats[64+tx] * (1.0f / N_NODES) - mean*mean;
      float scale = g[tx] * rsqrtf(var + 1e-5f);
      ssl[tx] = scale; ssl[64+tx] = be[tx] - mean*scale;
    }
    __syncthreads();
  }
  const int row0 = blockIdx.x * 32;
  for (int i = tx; i < 32*(K/4); i += 256) {
    int row = i / (K/4), kq = i % (K/4);
    int grow = row0 + row;
    f4 v = {0.f,0.f,0.f,0.f};
    if (grow < N_NODES) {
      v = *(const f4*)&in[grow*K + kq*4];
      if (BN) {
        int c = kq*4;
        v.x = fmaxf(0.f, fmaf(v.x, ssl[c+0], ssl[64+c+0]));
        v.y = fmaxf(0.f, fmaf(v.y, ssl[c+1], ssl[64+c+1]));
        v.z = fmaxf(0.f, fmaf(v.z, ssl[c+2], ssl[64+c+2]));
        v.w = fmaxf(0.f, fmaf(v.w, ssl[c+3], ssl[64+c+3]));
      }
    }
    *(f4*)&xs[row*K + kq*4] = v;
  }
  const int c0 = (tx & 31) * 4;
  const int r0 = (tx >> 5) * 4;
  float acc[4][4] = {};
  for (int chunk = 0; chunk < K/64; ++chunk) {
    if (chunk) __syncthreads();
    for (int i = tx; i < 64*32; i += 256) ((f4*)wt)[i] = ((const f4*)(wtg + chunk*64*128))[i];
    __syncthreads();
    #pragma unroll 4
    for (int kk = 0; kk < 64; ++kk) {
      const int k = chunk*64 + kk;
      f4 wv = *(const f4*)&wt[kk*128 + c0];
      float x0 = xs[(r0+0)*K + k];
      float x1 = xs[(r0+1)*K + k];
      float x2 = xs[(r0+2)*K + k];
      float x3 = xs[(r0+3)*K + k];
      acc[0][0] = fmaf(x0, wv.x, acc[0][0]); acc[0][1] = fmaf(x0, wv.y, acc[0][1]);
      acc[0][2] = fmaf(x0, wv.z, acc[0][2]); acc[0][3] = fmaf(x0, wv.w, acc[0][3]);
      acc[1][0] = fmaf(x1, wv.x, acc[1][0]); acc[1][1] = fmaf(x1, wv.y, acc[1][1]);
      acc[1][2] = fmaf(x1, wv.z, acc[1][2]); acc[1][3] = fmaf(x1, wv.w, acc[1][3]);
      acc[2][0] = fmaf(x2, wv.x, acc[2][0]); acc[2][1] = fmaf(x2, wv.y, acc[2][1]);
      acc[2][2] = fmaf(x2, wv.z, acc[2][2]); acc[2][3] = fmaf(x2, wv.w, acc[2][3]);
      acc[3][0] = fmaf(x3, wv.x, acc[3][0]); acc[3][1] = fmaf(x3, wv.y, acc[3][1]);
      acc[3][2] = fmaf(x3, wv.z, acc[3][2]); acc[3][3] = fmaf(x3, wv.w, acc[3][3]);
    }
  }
  const bool second = (c0 >= 64);
  if (second) {
    const int cc = c0 - 64;
    f4 bv = *(const f4*)&bias2[cc];
    #pragma unroll
    for (int r = 0; r < 4; ++r) {
      int grow = row0 + r0 + r;
      if (grow < N_NODES) {
        f4 o;
        o.x = acc[r][0] + bv.x; o.y = acc[r][1] + bv.y;
        o.z = acc[r][2] + bv.z; o.w = acc[r][3] + bv.w;
        *(f4*)&out2[grow*64 + cc] = o;
      }
    }
  } else {
    const int slice = c0 >> 4, coff = c0 & 15;
    unsigned short* __restrict__ op = out1 + (size_t)slice * (N_NODES*16);
    #pragma unroll
    for (int r = 0; r < 4; ++r) {
      int grow = row0 + r0 + r;
      if (grow < N_NODES) {
        ushort4 o;
        o.x = f2bf(acc[r][0]); o.y = f2bf(acc[r][1]);
        o.z = f2bf(acc[r][2]); o.w = f2bf(acc[r][3]);
        *(ushort4*)&op[grow*16 + coff] = o;
      }
    }
  }
}

// ------------- final dual GEMM: K=192 via 3 chunks of 64, 80 out channels -------------
__global__ __launch_bounds__(320) void k_gemm_final(
    const float* __restrict__ hpre, const float* __restrict__ stats,
    const float* __restrict__ g, const float* __restrict__ be,
    const float* __restrict__ af, const float* __restrict__ wtg,
    const float* __restrict__ bc,
    unsigned short* __restrict__ yl, float* __restrict__ yr) {
  __shared__ float wt[64*80];
  __shared__ float xs[64*65];
  __shared__ float ssl[128];
  const int tx = threadIdx.x;
  if (tx < 64) {
    float mean = stats[tx] * (1.0f / N_NODES);
    float var  = stats[64+tx] * (1.0f / N_NODES) - mean*mean;
    float scale = g[tx] * rsqrtf(var + 1e-5f);
    ssl[tx] = scale; ssl[64+tx] = be[tx] - mean*scale;
  }
  const int row0 = blockIdx.x * 64;
  const int c0 = (tx % 20) * 4;
  const int r0 = (tx / 20) * 4;
  float acc[4][4] = {};
  for (int chunk = 0; chunk < 3; ++chunk) {
    __syncthreads();
    for (int i = tx; i < 64*20; i += 320) ((f4*)wt)[i] = ((const f4*)(wtg + chunk*64*80))[i];
    for (int i = tx; i < 64*16; i += 320) {
      int row = i >> 4, p = i & 15;
      int grow = row0 + row;
      f4 v = {0.f,0.f,0.f,0.f};
      if (grow < N_NODES) {
        if (chunk == 0) {
          int c = p*4;
          v = *(const f4*)&hpre[grow*64 + c];
          v.x = fmaxf(0.f, fmaf(v.x, ssl[c+0], ssl[64+c+0]));
          v.y = fmaxf(0.f, fmaf(v.y, ssl[c+1], ssl[64+c+1]));
          v.z = fmaxf(0.f, fmaf(v.z, ssl[c+2], ssl[64+c+2]));
          v.w = fmaxf(0.f, fmaf(v.w, ssl[c+3], ssl[64+c+3]));
        } else {
          v = *(const f4*)&af[grow*128 + (chunk-1)*64 + p*4];
        }
      }
      *(f4*)&xs[row*65 + p*4] = v;
    }
    __syncthreads();
    #pragma unroll 4
    for (int kk = 0; kk < 64; ++kk) {
      f4 wv = *(const f4*)&wt[kk*80 + c0];
      float x0 = xs[(r0+0)*65 + kk];
      float x1 = xs[(r0+1)*65 + kk];
      float x2 = xs[(r0+2)*65 + kk];
      float x3 = xs[(r0+3)*65 + kk];
      acc[0][0] = fmaf(x0, wv.x, acc[0][0]); acc[0][1] = fmaf(x0, wv.y, acc[0][1]);
      acc[0][2] = fmaf(x0, wv.z, acc[0][2]); acc[0][3] = fmaf(x0, wv.w, acc[0][3]);
      acc[1][0] = fmaf(x1, wv.x, acc[1][0]); acc[1][1] = fmaf(x1, wv.y, acc[1][1]);
      acc[1][2] = fmaf(x1, wv.z, acc[1][2]); acc[1][3] = fmaf(x1, wv.w, acc[1][3]);
      acc[2][0] = fmaf(x2, wv.x, acc[2][0]); acc[2][1] = fmaf(x2, wv.y, acc[2][1]);
      acc[2][2] = fmaf(x2, wv.z, acc[2][2]); acc[2][3] = fmaf(x2, wv.w, acc[2][3]);
      acc[3][0] = fmaf(x3, wv.x, acc[3][0]); acc[3][1] = fmaf(x3, wv.y, acc[3][1]);
      acc[3][2] = fmaf(x3, wv.z, acc[3][2]); acc[3][3] = fmaf(x3, wv.w, acc[3][3]);
    }
  }
  const bool second = (c0 >= 40);
  if (second) {
    const int cc = c0 - 40;
    f4 bv = *(const f4*)&bc[40 + cc];
    #pragma unroll
    for (int r = 0; r < 4; ++r) {
      int grow = row0 + r0 + r;
      if (grow < N_NODES) {
        f4 o;
        o.x = acc[r][0] + bv.x; o.y = acc[r][1] + bv.y;
        o.z = acc[r][2] + bv.z; o.w = acc[r][3] + bv.w;
        *(f4*)&yr[grow*40 + cc] = o;
      }
    }
  } else {
    f4 bv = *(const f4*)&bc[c0];
    #pragma unroll
    for (int r = 0; r < 4; ++r) {
      int grow = row0 + r0 + r;
      if (grow < N_NODES) {
        ushort4 o;
        o.x = f2bf(acc[r][0] + bv.x); o.y = f2bf(acc[r][1] + bv.y);
        o.z = f2bf(acc[r][2] + bv.z); o.w = f2bf(acc[r][3] + bv.w);
        *(ushort4*)&yl[grow*40 + c0] = o;
      }
    }
  }
}

// ------------- channel-sliced CSR gather: slice table 3.2MB -> L2-resident -------------
// grid = 4*GBLK; slice = blockIdx.x/GBLK (quasi-sequential -> temporal L2 separation)
// lane = eg*4+cl: eg=edge group (0..15), cl=channel quad (0..3); 16 edges per load instr
__global__ __launch_bounds__(256) void k_gather_slice(
    const int* __restrict__ rowptr, const int* __restrict__ srcs,
    const unsigned short* __restrict__ y,   // slice-major [4][N][16]
    const float* __restrict__ yr, const float* __restrict__ invd,
    float* __restrict__ hpre, float* __restrict__ stats) {
  __shared__ float ssum[16], ssq[16];
  __shared__ int slds[SMAX];
  const int t = threadIdx.x;
  const int lane = t & 63, w = t >> 6;
  const int eg = lane >> 2;     // 0..15
  const int cl = lane & 3;      // 0..3
  const int slice = blockIdx.x / GBLK;
  const int blk   = blockIdx.x - slice * GBLK;
  const unsigned short* __restrict__ ys = y + (size_t)slice * (N_NODES*16);
  const int nblk = blk * 16;
  if (t < 16) { ssum[t] = 0.f; ssq[t] = 0.f; }
  const int boff = rowptr[nblk];
  const int tot  = rowptr[nblk + 16] - boff;
  const bool useLds = (tot <= SMAX);
  if (useLds) {
    for (int i = t; i < tot; i += 256) slds[i] = srcs[boff + i];
  }
  __syncthreads();
  const int* __restrict__ ep = useLds ? slds : srcs + boff;
  const int node0 = nblk + w * 4;
  float ps0 = 0.f, ps1 = 0.f, ps2 = 0.f, ps3 = 0.f;
  float pq0 = 0.f, pq1 = 0.f, pq2 = 0.f, pq3 = 0.f;
  for (int n = 0; n < 4; ++n) {
    const int node = node0 + n;
    const int jb = rowptr[node] - boff, je = rowptr[node + 1] - boff;
    float a0 = 0.f, a1 = 0.f, a2 = 0.f, a3 = 0.f;
    int j = jb;
    for (; j + 32 <= je; j += 32) {
      int s0 = ep[j + eg];
      int s1 = ep[j + 16 + eg];
      uint2 va = *(const uint2*)&ys[(size_t)s0 * 16 + (cl << 2)];
      uint2 vb = *(const uint2*)&ys[(size_t)s1 * 16 + (cl << 2)];
      a0 += bfLO(va.x) + bfLO(vb.x); a1 += bfHI(va.x) + bfHI(vb.x);
      a2 += bfLO(va.y) + bfLO(vb.y); a3 += bfHI(va.y) + bfHI(vb.y);
    }
    if (j + 16 <= je) {
      int s0 = ep[j + eg];
      uint2 va = *(const uint2*)&ys[(size_t)s0 * 16 + (cl << 2)];
      a0 += bfLO(va.x); a1 += bfHI(va.x); a2 += bfLO(va.y); a3 += bfHI(va.y);
      j += 16;
    }
    {
      int rem = je - j;
      if (eg < rem) {
        int s0 = ep[j + eg];
        uint2 va = *(const uint2*)&ys[(size_t)s0 * 16 + (cl << 2)];
        a0 += bfLO(va.x); a1 += bfHI(va.x); a2 += bfLO(va.y); a3 += bfHI(va.y);
      }
    }
    // fold the 16 edge groups (lane bits 2..5)
    a0 += __shfl_xor(a0, 4, 64);  a1 += __shfl_xor(a1, 4, 64);
    a2 += __shfl_xor(a2, 4, 64);  a3 += __shfl_xor(a3, 4, 64);
    a0 += __shfl_xor(a0, 8, 64);  a1 += __shfl_xor(a1, 8, 64);
    a2 += __shfl_xor(a2, 8, 64);  a3 += __shfl_xor(a3, 8, 64);
    a0 += __shfl_xor(a0, 16, 64); a1 += __shfl_xor(a1, 16, 64);
    a2 += __shfl_xor(a2, 16, 64); a3 += __shfl_xor(a3, 16, 64);
    a0 += __shfl_xor(a0, 32, 64); a1 += __shfl_xor(a1, 32, 64);
    a2 += __shfl_xor(a2, 32, 64); a3 += __shfl_xor(a3, 32, 64);
    if (eg == 0) {
      float inv = invd[node];
      f4 yv = *(const f4*)&yr[(size_t)node * 64 + slice * 16 + (cl << 2)];
      f4 h;
      h.x = fmaf(a0, inv, yv.x); h.y = fmaf(a1, inv, yv.y);
      h.z = fmaf(a2, inv, yv.z); h.w = fmaf(a3, inv, yv.w);
      *(f4*)&hpre[(size_t)node * 64 + slice * 16 + (cl << 2)] = h;
      ps0 += h.x; ps1 += h.y; ps2 += h.z; ps3 += h.w;
      pq0 += h.x*h.x; pq1 += h.y*h.y; pq2 += h.z*h.z; pq3 += h.w*h.w;
    }
  }
  if (eg == 0) {
    atomicAdd(&ssum[(cl<<2)+0], ps0); atomicAdd(&ssum[(cl<<2)+1], ps1);
    atomicAdd(&ssum[(cl<<2)+2], ps2); atomicAdd(&ssum[(cl<<2)+3], ps3);
    atomicAdd(&ssq[(cl<<2)+0], pq0); atomicAdd(&ssq[(cl<<2)+1], pq1);
    atomicAdd(&ssq[(cl<<2)+2], pq2); atomicAdd(&ssq[(cl<<2)+3], pq3);
  }
  __syncthreads();
  if (t < 16) {
    atomicAdd(&stats[slice*16 + t], ssum[t]);
    atomicAdd(&stats[64 + slice*16 + t], ssq[t]);
  }
}

// ------------- CSR gather (40ch bf16) + log_softmax, LDS-staged indices -------------
__global__ __launch_bounds__(256) void k_gather_out(
    const int* __restrict__ rowptr, const int* __restrict__ srcs,
    const unsigned short* __restrict__ y, const float* __restrict__ yr,
    const float* __restrict__ invd, float* __restrict__ out) {
  __shared__ int slds[SMAX];
  const int t = threadIdx.x;
  const int lane = t & 63, w = t >> 6;
  const int nblk = blockIdx.x * 16;
  const int boff = rowptr[nblk];
  const int tot  = rowptr[nblk + 16] - boff;
  const bool useLds = (tot <= SMAX);
  if (useLds) {
    for (int i = t; i < tot; i += 256) slds[i] = srcs[boff + i];
  }
  __syncthreads();
  const int* __restrict__ ep = useLds ? slds : srcs + boff;
  const int node0 = nblk + w * 4;
  #pragma unroll
  for (int n = 0; n < 4; ++n) {
    const int node = node0 + n;
    const int jb = rowptr[node] - boff, je = rowptr[node + 1] - boff;
    float acc = 0.f;
    if (lane < 40) {
      int j = jb;
      for (; j + 16 <= je; j += 16) {
        int s[16];
        #pragma unroll
        for (int i = 0; i < 16; ++i) s[i] = ep[j + i];
        float v[16];
        #pragma unroll
        for (int i = 0; i < 16; ++i) v[i] = bf2f(y[s[i] * 40 + lane]);
        #pragma unroll
        for (int st = 1; st < 16; st <<= 1)
          #pragma unroll
          for (int i = 0; i < 16; i += 2 * st) v[i] += v[i + st];
        acc += v[0];
      }
      if (j + 8 <= je) {
        int s[8];
        #pragma unroll
        for (int i = 0; i < 8; ++i) s[i] = ep[j + i];
        float v[8];
        #pragma unroll
        for (int i = 0; i < 8; ++i) v[i] = bf2f(y[s[i] * 40 + lane]);
        acc += ((v[0] + v[1]) + (v[2] + v[3])) + ((v[4] + v[5]) + (v[6] + v[7]));
        j += 8;
      }
      if (j + 4 <= je) {
        int s0 = ep[j+0], s1 = ep[j+1], s2 = ep[j+2], s3 = ep[j+3];
        float v0 = bf2f(y[s0*40 + lane]);
        float v1 = bf2f(y[s1*40 + lane]);
        float v2 = bf2f(y[s2*40 + lane]);
        float v3 = bf2f(y[s3*40 + lane]);
        acc += (v0 + v1) + (v2 + v3);
        j += 4;
      }
      for (; j < je; ++j) acc += bf2f(y[ep[j] * 40 + lane]);
    }
    float v = (lane < 40) ? fmaf(acc, invd[node], yr[node * 40 + lane]) : -1e30f;
    float m = v;
    #pragma unroll
    for (int off = 32; off >= 1; off >>= 1) m = fmaxf(m, __shfl_xor(m, off, 64));
    float e_ = (lane < 40) ? __expf(v - m) : 0.f;
    float s_ = e_;
    #pragma unroll
    for (int off = 32; off >= 1; off >>= 1) s_ += __shfl_xor(s_, off, 64);
    if (lane < 40) out[node * 40 + lane] = v - m - __logf(s_);
  }
}

extern "C" void kernel_launch(void* const* d_in, const int* in_sizes, int n_in,
                              void* d_out, int out_size, void* d_ws, size_t ws_size,
                              hipStream_t stream) {
  const float* x   = (const float*)d_in[0];
  const int*   esrc = (const int*)d_in[1];
  const int*   edst = (const int*)d_in[2];
  const float* af  = (const float*)d_in[3];
  const float* Wl0 = (const float*)d_in[4];
  const float* Wr0 = (const float*)d_in[5];
  const float* b0  = (const float*)d_in[6];
  const float* g0  = (const float*)d_in[7];
  const float* be0 = (const float*)d_in[8];
  const float* Wl1 = (const float*)d_in[9];
  const float* Wr1 = (const float*)d_in[10];
  const float* b1  = (const float*)d_in[11];
  const float* g1  = (const float*)d_in[12];
  const float* be1 = (const float*)d_in[13];
  const float* Wf  = (const float*)d_in[14];
  const float* bfv = (const float*)d_in[15];
  const float* Wl2 = (const float*)d_in[16];
  const float* Wr2 = (const float*)d_in[17];
  const float* b2  = (const float*)d_in[18];

  float* ws   = (float*)d_ws;
  float* invd = ws;                          // N
  float* bufA = ws + (size_t)100000;         // N*64 region; slice-major bf16 msgs / bf16 yl
  float* bufB = bufA + (size_t)6400000;      // N*64 (h_pre)
  float* bufC = bufB + (size_t)6400000;      // N*64 (yr stage; 40ch in final layer)
  float* stats = bufC + (size_t)6400000;     // 512 (layer0 raw @0, layer1 raw @128)
  float* Wcl  = stats + 512;                 // 40*128
  float* Wcr  = Wcl + 5120;                  // 40*128
  float* bc   = Wcr + 5120;                  // 80
  float* WT0  = bc + 80;                     // 128*128
  float* WT1  = WT0 + 16384;                 // 64*128
  float* WTF  = WT1 + 8192;                  // 192*80
  int*   counts = (int*)(WTF + 15360);       // N (aliased as cursor)
  int*   rowptr = counts + 100000;           // N+1
  int*   srcs   = rowptr + 100001;           // E
  int*   blk    = srcs + N_EDGES;            // SCAN_NBLK
  unsigned short* msg = (unsigned short*)bufA;  // [4][N][16] bf16 slice-major
  unsigned short* ylb = (unsigned short*)bufA;  // N*40 bf16 (final layer)
  float* out  = (float*)d_out;

  // ---- CSR build (reused by all 3 layers) ----
  hipMemsetAsync(counts, 0, 100000*sizeof(int), stream);
  hipMemsetAsync(stats, 0, 512*sizeof(float), stream);
  k_count<<<6250, 256, 0, stream>>>(edst, counts);
  k_scan_a<<<SCAN_NBLK, 256, 0, stream>>>(counts, blk);
  k_scan_b<<<1, 128, 0, stream>>>(blk);
  k_scan_c<<<SCAN_NBLK, 256, 0, stream>>>(counts, blk, rowptr, counts /*cursor alias*/, invd);
  k_place<<<6250, 256, 0, stream>>>(esrc, edst, counts, srcs);

  k_precomp<<<40, 128, 0, stream>>>(Wl2, Wr2, Wf, bfv, b2, Wcl, Wcr, bc);
  k_buildwt<128><<<64, 256, 0, stream>>>(Wl0, Wr0, WT0);
  k_buildwt<64><<<32, 256, 0, stream>>>(Wl1, Wr1, WT1);
  k_buildwtf<<<60, 256, 0, stream>>>(Wl2, Wr2, Wcl, Wcr, WTF);

  // ---- layer 0 ----
  k_gemm_dual<128,false><<<3125, 256, 0, stream>>>(x, nullptr, nullptr, nullptr, WT0, b0, msg, bufC);
  k_gather_slice<<<4*GBLK, 256, 0, stream>>>(rowptr, srcs, msg, bufC, invd, bufB, stats);

  // ---- layer 1 (BN from layer-0 raw stats, fused) ----
  k_gemm_dual<64,true><<<3125, 256, 0, stream>>>(bufB, stats, g0, be0, WT1, b1, msg, bufC);
  k_gather_slice<<<4*GBLK, 256, 0, stream>>>(rowptr, srcs, msg, bufC, invd, bufB, stats + 128);

  // ---- final layer (BN from layer-1 raw stats, fused; concat folded; yl bf16) ----
  k_gemm_final<<<1563, 320, 0, stream>>>(bufB, stats + 128, g1, be1, af, WTF, bc, ylb, bufC);
  k_gather_out<<<6250, 256, 0, stream>>>(rowptr, srcs, ylb, bufC, invd, out);
}

// Round 11
// 759.734 us; speedup vs baseline: 1.1906x; 1.1906x over previous
//
#include <hip/hip_runtime.h>

#define N_NODES 100000
#define N_EDGES 1600000
#define SCAN_NBLK 98   // ceil(100000/1024)
#define SMAX 1024      // staged edges per block (16 nodes, mean 256)

typedef float4 f4;

__device__ __forceinline__ float bf2f(unsigned short v) {
  return __uint_as_float(((unsigned)v) << 16);
}
__device__ __forceinline__ unsigned short f2bf(float f) {
  unsigned u = __float_as_uint(f);
  u += 0x7FFF + ((u >> 16) & 1);   // round-to-nearest-even
  return (unsigned short)(u >> 16);
}
__device__ __forceinline__ float bfLO(unsigned u) { return __uint_as_float(u << 16); }
__device__ __forceinline__ float bfHI(unsigned u) { return __uint_as_float(u & 0xFFFF0000u); }

// ---------------- CSR build ----------------
__global__ __launch_bounds__(256) void k_count(const int* __restrict__ dst, int* __restrict__ counts) {
  int i = blockIdx.x * 256 + threadIdx.x;
  if (i < N_EDGES) atomicAdd(&counts[dst[i]], 1);
}

__global__ __launch_bounds__(256) void k_scan_a(const int* __restrict__ counts, int* __restrict__ blk) {
  __shared__ int red[256];
  const int t = threadIdx.x;
  const int base = blockIdx.x * 1024;
  int s = 0;
  #pragma unroll
  for (int i = 0; i < 4; ++i) {
    int idx = base + t + i * 256;
    if (idx < N_NODES) s += counts[idx];
  }
  red[t] = s; __syncthreads();
  for (int off = 128; off >= 1; off >>= 1) {
    if (t < off) red[t] += red[t + off];
    __syncthreads();
  }
  if (t == 0) blk[blockIdx.x] = red[0];
}

__global__ __launch_bounds__(128) void k_scan_b(int* __restrict__ blk) {
  __shared__ int v[128];
  const int t = threadIdx.x;
  int val = (t < SCAN_NBLK) ? blk[t] : 0;
  v[t] = val; __syncthreads();
  for (int off = 1; off < 128; off <<= 1) {
    int a = (t >= off) ? v[t - off] : 0;
    __syncthreads();
    v[t] += a;
    __syncthreads();
  }
  if (t < SCAN_NBLK) blk[t] = v[t] - val;  // exclusive
}

__global__ __launch_bounds__(256) void k_scan_c(const int* __restrict__ counts, const int* __restrict__ blkoff,
                                                int* __restrict__ rowptr, int* __restrict__ cursor,
                                                float* __restrict__ invd) {
  __shared__ int ps[256];
  const int t = threadIdx.x;
  const int base = blockIdx.x * 1024 + t * 4;
  int c[4]; int s = 0;
  #pragma unroll
  for (int i = 0; i < 4; ++i) {
    int idx = base + i;
    c[i] = (idx < N_NODES) ? counts[idx] : 0;
    s += c[i];
  }
  ps[t] = s; __syncthreads();
  for (int off = 1; off < 256; off <<= 1) {
    int a = (t >= off) ? ps[t - off] : 0;
    __syncthreads();
    ps[t] += a;
    __syncthreads();
  }
  int run = blkoff[blockIdx.x] + ps[t] - s;
  #pragma unroll
  for (int i = 0; i < 4; ++i) {
    int idx = base + i;
    if (idx < N_NODES) {
      rowptr[idx] = run;
      cursor[idx] = run;
      invd[idx] = 1.0f / fmaxf((float)c[i], 1.0f);
      run += c[i];
      if (idx == N_NODES - 1) rowptr[N_NODES] = run;
    }
  }
}

__global__ __launch_bounds__(256) void k_place(const int* __restrict__ src, const int* __restrict__ dst,
                                               int* __restrict__ cursor, int* __restrict__ srcs) {
  int e = blockIdx.x * 256 + threadIdx.x;
  if (e < N_EDGES) {
    int pos = atomicAdd(&cursor[dst[e]], 1);
    srcs[pos] = src[e];
  }
}

// ------------- combined projection weights for final layer -------------
__global__ void k_precomp(const float* __restrict__ Wl2, const float* __restrict__ Wr2,
                          const float* __restrict__ Wf, const float* __restrict__ bfv,
                          const float* __restrict__ b2,
                          float* __restrict__ Wcl, float* __restrict__ Wcr, float* __restrict__ bc) {
  int o = blockIdx.x, k = threadIdx.x;  // o<40, k<128
  float al = 0.f, ar = 0.f;
  for (int j = 0; j < 64; ++j) {
    float wl = Wl2[o*128 + 64 + j], wr = Wr2[o*128 + 64 + j];
    float wf = Wf[j*128 + k];
    al = fmaf(wl, wf, al); ar = fmaf(wr, wf, ar);
  }
  Wcl[o*128 + k] = al; Wcr[o*128 + k] = ar;
  if (k == 0) {
    float sl = 0.f, sr = 0.f;
    for (int j = 0; j < 64; ++j) { sl += Wl2[o*128+64+j]*bfv[j]; sr += Wr2[o*128+64+j]*bfv[j]; }
    bc[o] = sl; bc[40+o] = sr + b2[o];
  }
}

template<int K>
__global__ __launch_bounds__(256) void k_buildwt(const float* __restrict__ W1, const float* __restrict__ W2,
                                                 float* __restrict__ dst) {
  int idx = blockIdx.x * 256 + threadIdx.x;
  if (idx >= K*128) return;
  int c = idx & 127, k = idx >> 7;
  dst[idx] = (c < 64) ? W1[c*K + k] : W2[(c-64)*K + k];
}

__global__ __launch_bounds__(256) void k_buildwtf(const float* __restrict__ Wl2, const float* __restrict__ Wr2,
                                                  const float* __restrict__ Wcl, const float* __restrict__ Wcr,
                                                  float* __restrict__ dst) {
  int idx = blockIdx.x * 256 + threadIdx.x;
  if (idx >= 192*80) return;
  int c = idx % 80, k = idx / 80;
  float w;
  if (k < 64) w = (c < 40) ? Wl2[c*128 + k] : Wr2[(c-40)*128 + k];
  else        w = (c < 40) ? Wcl[c*128 + k-64] : Wcr[(c-40)*128 + k-64];
  dst[idx] = w;
}

// ------------- dual GEMM: out1(bf16) = in@W1.T, out2(f32) = in@W2.T + bias2 -------------
// BN scale/shift computed in-kernel from raw stats (fused k_bnparams)
template<int K, bool BN>
__global__ __launch_bounds__(256) void k_gemm_dual(
    const float* __restrict__ in, const float* __restrict__ stats,
    const float* __restrict__ g, const float* __restrict__ be,
    const float* __restrict__ wtg, const float* __restrict__ bias2,
    unsigned short* __restrict__ out1, float* __restrict__ out2) {
  __shared__ float wt[64*128];
  __shared__ float xs[32*K];
  __shared__ float ssl[128];
  const int tx = threadIdx.x;
  if (BN) {
    if (tx < 64) {
      float mean = stats[tx] * (1.0f / N_NODES);
      float var  = stats[64+tx] * (1.0f / N_NODES) - mean*mean;
      float scale = g[tx] * rsqrtf(var + 1e-5f);
      ssl[tx] = scale; ssl[64+tx] = be[tx] - mean*scale;
    }
    __syncthreads();
  }
  const int row0 = blockIdx.x * 32;
  for (int i = tx; i < 32*(K/4); i += 256) {
    int row = i / (K/4), kq = i % (K/4);
    int grow = row0 + row;
    f4 v = {0.f,0.f,0.f,0.f};
    if (grow < N_NODES) {
      v = *(const f4*)&in[grow*K + kq*4];
      if (BN) {
        int c = kq*4;
        v.x = fmaxf(0.f, fmaf(v.x, ssl[c+0], ssl[64+c+0]));
        v.y = fmaxf(0.f, fmaf(v.y, ssl[c+1], ssl[64+c+1]));
        v.z = fmaxf(0.f, fmaf(v.z, ssl[c+2], ssl[64+c+2]));
        v.w = fmaxf(0.f, fmaf(v.w, ssl[c+3], ssl[64+c+3]));
      }
    }
    *(f4*)&xs[row*K + kq*4] = v;
  }
  const int c0 = (tx & 31) * 4;
  const int r0 = (tx >> 5) * 4;
  float acc[4][4] = {};
  for (int chunk = 0; chunk < K/64; ++chunk) {
    if (chunk) __syncthreads();
    for (int i = tx; i < 64*32; i += 256) ((f4*)wt)[i] = ((const f4*)(wtg + chunk*64*128))[i];
    __syncthreads();
    #pragma unroll 4
    for (int kk = 0; kk < 64; ++kk) {
      const int k = chunk*64 + kk;
      f4 wv = *(const f4*)&wt[kk*128 + c0];
      float x0 = xs[(r0+0)*K + k];
      float x1 = xs[(r0+1)*K + k];
      float x2 = xs[(r0+2)*K + k];
      float x3 = xs[(r0+3)*K + k];
      acc[0][0] = fmaf(x0, wv.x, acc[0][0]); acc[0][1] = fmaf(x0, wv.y, acc[0][1]);
      acc[0][2] = fmaf(x0, wv.z, acc[0][2]); acc[0][3] = fmaf(x0, wv.w, acc[0][3]);
      acc[1][0] = fmaf(x1, wv.x, acc[1][0]); acc[1][1] = fmaf(x1, wv.y, acc[1][1]);
      acc[1][2] = fmaf(x1, wv.z, acc[1][2]); acc[1][3] = fmaf(x1, wv.w, acc[1][3]);
      acc[2][0] = fmaf(x2, wv.x, acc[2][0]); acc[2][1] = fmaf(x2, wv.y, acc[2][1]);
      acc[2][2] = fmaf(x2, wv.z, acc[2][2]); acc[2][3] = fmaf(x2, wv.w, acc[2][3]);
      acc[3][0] = fmaf(x3, wv.x, acc[3][0]); acc[3][1] = fmaf(x3, wv.y, acc[3][1]);
      acc[3][2] = fmaf(x3, wv.z, acc[3][2]); acc[3][3] = fmaf(x3, wv.w, acc[3][3]);
    }
  }
  const bool second = (c0 >= 64);
  if (second) {
    const int cc = c0 - 64;
    f4 bv = *(const f4*)&bias2[cc];
    #pragma unroll
    for (int r = 0; r < 4; ++r) {
      int grow = row0 + r0 + r;
      if (grow < N_NODES) {
        f4 o;
        o.x = acc[r][0] + bv.x; o.y = acc[r][1] + bv.y;
        o.z = acc[r][2] + bv.z; o.w = acc[r][3] + bv.w;
        *(f4*)&out2[grow*64 + cc] = o;
      }
    }
  } else {
    #pragma unroll
    for (int r = 0; r < 4; ++r) {
      int grow = row0 + r0 + r;
      if (grow < N_NODES) {
        ushort4 o;
        o.x = f2bf(acc[r][0]); o.y = f2bf(acc[r][1]);
        o.z = f2bf(acc[r][2]); o.w = f2bf(acc[r][3]);
        *(ushort4*)&out1[grow*64 + c0] = o;
      }
    }
  }
}

// ------------- final dual GEMM: K=192 via 3 chunks of 64, 80 out channels -------------
// LDS: wt 20.5KB + xs 16.6KB + ssl 0.5KB = 37.6KB -> 4 blocks/CU. BN fused from raw stats.
__global__ __launch_bounds__(320) void k_gemm_final(
    const float* __restrict__ hpre, const float* __restrict__ stats,
    const float* __restrict__ g, const float* __restrict__ be,
    const float* __restrict__ af, const float* __restrict__ wtg,
    const float* __restrict__ bc,
    unsigned short* __restrict__ yl, float* __restrict__ yr) {
  __shared__ float wt[64*80];
  __shared__ float xs[64*65];
  __shared__ float ssl[128];
  const int tx = threadIdx.x;
  if (tx < 64) {
    float mean = stats[tx] * (1.0f / N_NODES);
    float var  = stats[64+tx] * (1.0f / N_NODES) - mean*mean;
    float scale = g[tx] * rsqrtf(var + 1e-5f);
    ssl[tx] = scale; ssl[64+tx] = be[tx] - mean*scale;
  }
  const int row0 = blockIdx.x * 64;
  const int c0 = (tx % 20) * 4;
  const int r0 = (tx / 20) * 4;
  float acc[4][4] = {};
  for (int chunk = 0; chunk < 3; ++chunk) {
    __syncthreads();  // ssl ready (chunk 0) / prev compute done
    for (int i = tx; i < 64*20; i += 320) ((f4*)wt)[i] = ((const f4*)(wtg + chunk*64*80))[i];
    for (int i = tx; i < 64*16; i += 320) {
      int row = i >> 4, p = i & 15;
      int grow = row0 + row;
      f4 v = {0.f,0.f,0.f,0.f};
      if (grow < N_NODES) {
        if (chunk == 0) {
          int c = p*4;
          v = *(const f4*)&hpre[grow*64 + c];
          v.x = fmaxf(0.f, fmaf(v.x, ssl[c+0], ssl[64+c+0]));
          v.y = fmaxf(0.f, fmaf(v.y, ssl[c+1], ssl[64+c+1]));
          v.z = fmaxf(0.f, fmaf(v.z, ssl[c+2], ssl[64+c+2]));
          v.w = fmaxf(0.f, fmaf(v.w, ssl[c+3], ssl[64+c+3]));
        } else {
          v = *(const f4*)&af[grow*128 + (chunk-1)*64 + p*4];
        }
      }
      *(f4*)&xs[row*65 + p*4] = v;
    }
    __syncthreads();
    #pragma unroll 4
    for (int kk = 0; kk < 64; ++kk) {
      f4 wv = *(const f4*)&wt[kk*80 + c0];
      float x0 = xs[(r0+0)*65 + kk];
      float x1 = xs[(r0+1)*65 + kk];
      float x2 = xs[(r0+2)*65 + kk];
      float x3 = xs[(r0+3)*65 + kk];
      acc[0][0] = fmaf(x0, wv.x, acc[0][0]); acc[0][1] = fmaf(x0, wv.y, acc[0][1]);
      acc[0][2] = fmaf(x0, wv.z, acc[0][2]); acc[0][3] = fmaf(x0, wv.w, acc[0][3]);
      acc[1][0] = fmaf(x1, wv.x, acc[1][0]); acc[1][1] = fmaf(x1, wv.y, acc[1][1]);
      acc[1][2] = fmaf(x1, wv.z, acc[1][2]); acc[1][3] = fmaf(x1, wv.w, acc[1][3]);
      acc[2][0] = fmaf(x2, wv.x, acc[2][0]); acc[2][1] = fmaf(x2, wv.y, acc[2][1]);
      acc[2][2] = fmaf(x2, wv.z, acc[2][2]); acc[2][3] = fmaf(x2, wv.w, acc[2][3]);
      acc[3][0] = fmaf(x3, wv.x, acc[3][0]); acc[3][1] = fmaf(x3, wv.y, acc[3][1]);
      acc[3][2] = fmaf(x3, wv.z, acc[3][2]); acc[3][3] = fmaf(x3, wv.w, acc[3][3]);
    }
  }
  const bool second = (c0 >= 40);
  if (second) {
    const int cc = c0 - 40;
    f4 bv = *(const f4*)&bc[40 + cc];
    #pragma unroll
    for (int r = 0; r < 4; ++r) {
      int grow = row0 + r0 + r;
      if (grow < N_NODES) {
        f4 o;
        o.x = acc[r][0] + bv.x; o.y = acc[r][1] + bv.y;
        o.z = acc[r][2] + bv.z; o.w = acc[r][3] + bv.w;
        *(f4*)&yr[grow*40 + cc] = o;
      }
    }
  } else {
    f4 bv = *(const f4*)&bc[c0];
    #pragma unroll
    for (int r = 0; r < 4; ++r) {
      int grow = row0 + r0 + r;
      if (grow < N_NODES) {
        ushort4 o;
        o.x = f2bf(acc[r][0] + bv.x); o.y = f2bf(acc[r][1] + bv.y);
        o.z = f2bf(acc[r][2] + bv.z); o.w = f2bf(acc[r][3] + bv.w);
        *(ushort4*)&yl[grow*40 + c0] = o;
      }
    }
  }
}

// ------------- CSR gather (bf16 msgs), edge-parallel + LDS-staged indices -------------
template<bool STATS>
__global__ __launch_bounds__(256) void k_gather64(
    const int* __restrict__ rowptr, const int* __restrict__ srcs,
    const unsigned short* __restrict__ y, const float* __restrict__ yr,
    const float* __restrict__ invd, float* __restrict__ hpre, float* __restrict__ stats) {
  __shared__ float ssum[64], ssq[64];
  __shared__ int slds[SMAX];
  const int t = threadIdx.x;
  const int lane = t & 63, w = t >> 6;
  const int eg = lane >> 4;      // 0..3
  const int cl = lane & 15;      // 0..15
  const int nblk = blockIdx.x * 16;
  if (STATS && t < 64) { ssum[t] = 0.f; ssq[t] = 0.f; }
  const int boff = rowptr[nblk];
  const int tot  = rowptr[nblk + 16] - boff;
  const bool useLds = (tot <= SMAX);
  if (useLds) {
    for (int i = t; i < tot; i += 256) slds[i] = srcs[boff + i];
  }
  __syncthreads();
  const int* __restrict__ ep = useLds ? slds : srcs + boff;  // indices relative to boff
  const int node0 = nblk + w * 4;
  float ps0 = 0.f, ps1 = 0.f, ps2 = 0.f, ps3 = 0.f;
  float pq0 = 0.f, pq1 = 0.f, pq2 = 0.f, pq3 = 0.f;
  for (int n = 0; n < 4; ++n) {
    const int node = node0 + n;
    const int jb = rowptr[node] - boff, je = rowptr[node + 1] - boff;
    float a0 = 0.f, a1 = 0.f, a2 = 0.f, a3 = 0.f;
    int j = jb;
    for (; j + 16 <= je; j += 16) {
      int s0 = ep[j + eg];
      int s1 = ep[j + 4 + eg];
      int s2 = ep[j + 8 + eg];
      int s3 = ep[j + 12 + eg];
      uint2 va = *(const uint2*)&y[(size_t)s0 * 64 + (cl << 2)];
      uint2 vb = *(const uint2*)&y[(size_t)s1 * 64 + (cl << 2)];
      uint2 vc = *(const uint2*)&y[(size_t)s2 * 64 + (cl << 2)];
      uint2 vd = *(const uint2*)&y[(size_t)s3 * 64 + (cl << 2)];
      a0 += (bfLO(va.x) + bfLO(vb.x)) + (bfLO(vc.x) + bfLO(vd.x));
      a1 += (bfHI(va.x) + bfHI(vb.x)) + (bfHI(vc.x) + bfHI(vd.x));
      a2 += (bfLO(va.y) + bfLO(vb.y)) + (bfLO(vc.y) + bfLO(vd.y));
      a3 += (bfHI(va.y) + bfHI(vb.y)) + (bfHI(vc.y) + bfHI(vd.y));
    }
    for (; j + 4 <= je; j += 4) {
      int s0 = ep[j + eg];
      uint2 va = *(const uint2*)&y[(size_t)s0 * 64 + (cl << 2)];
      a0 += bfLO(va.x); a1 += bfHI(va.x); a2 += bfLO(va.y); a3 += bfHI(va.y);
    }
    {
      int rem = je - j;
      if (eg < rem) {
        int s0 = ep[j + eg];
        uint2 va = *(const uint2*)&y[(size_t)s0 * 64 + (cl << 2)];
        a0 += bfLO(va.x); a1 += bfHI(va.x); a2 += bfLO(va.y); a3 += bfHI(va.y);
      }
    }
    // fold the 4 edge groups (lane bits 4,5)
    a0 += __shfl_xor(a0, 16, 64); a1 += __shfl_xor(a1, 16, 64);
    a2 += __shfl_xor(a2, 16, 64); a3 += __shfl_xor(a3, 16, 64);
    a0 += __shfl_xor(a0, 32, 64); a1 += __shfl_xor(a1, 32, 64);
    a2 += __shfl_xor(a2, 32, 64); a3 += __shfl_xor(a3, 32, 64);
    if (eg == 0) {
      float inv = invd[node];
      f4 yv = *(const f4*)&yr[(size_t)node * 64 + (cl << 2)];
      f4 h;
      h.x = fmaf(a0, inv, yv.x); h.y = fmaf(a1, inv, yv.y);
      h.z = fmaf(a2, inv, yv.z); h.w = fmaf(a3, inv, yv.w);
      *(f4*)&hpre[(size_t)node * 64 + (cl << 2)] = h;
      if (STATS) {
        ps0 += h.x; ps1 += h.y; ps2 += h.z; ps3 += h.w;
        pq0 += h.x*h.x; pq1 += h.y*h.y; pq2 += h.z*h.z; pq3 += h.w*h.w;
      }
    }
  }
  if (STATS) {
    if (eg == 0) {
      atomicAdd(&ssum[(cl<<2)+0], ps0); atomicAdd(&ssum[(cl<<2)+1], ps1);
      atomicAdd(&ssum[(cl<<2)+2], ps2); atomicAdd(&ssum[(cl<<2)+3], ps3);
      atomicAdd(&ssq[(cl<<2)+0], pq0); atomicAdd(&ssq[(cl<<2)+1], pq1);
      atomicAdd(&ssq[(cl<<2)+2], pq2); atomicAdd(&ssq[(cl<<2)+3], pq3);
    }
    __syncthreads();
    if (t < 64) { atomicAdd(&stats[t], ssum[t]); atomicAdd(&stats[64 + t], ssq[t]); }
  }
}

// ------------- CSR gather (40ch bf16) + log_softmax, LDS-staged indices -------------
__global__ __launch_bounds__(256) void k_gather_out(
    const int* __restrict__ rowptr, const int* __restrict__ srcs,
    const unsigned short* __restrict__ y, const float* __restrict__ yr,
    const float* __restrict__ invd, float* __restrict__ out) {
  __shared__ int slds[SMAX];
  const int t = threadIdx.x;
  const int lane = t & 63, w = t >> 6;
  const int nblk = blockIdx.x * 16;
  const int boff = rowptr[nblk];
  const int tot  = rowptr[nblk + 16] - boff;
  const bool useLds = (tot <= SMAX);
  if (useLds) {
    for (int i = t; i < tot; i += 256) slds[i] = srcs[boff + i];
  }
  __syncthreads();
  const int* __restrict__ ep = useLds ? slds : srcs + boff;
  const int node0 = nblk + w * 4;
  #pragma unroll
  for (int n = 0; n < 4; ++n) {
    const int node = node0 + n;
    const int jb = rowptr[node] - boff, je = rowptr[node + 1] - boff;
    float acc = 0.f;
    if (lane < 40) {
      int j = jb;
      for (; j + 16 <= je; j += 16) {
        int s[16];
        #pragma unroll
        for (int i = 0; i < 16; ++i) s[i] = ep[j + i];
        float v[16];
        #pragma unroll
        for (int i = 0; i < 16; ++i) v[i] = bf2f(y[s[i] * 40 + lane]);
        #pragma unroll
        for (int st = 1; st < 16; st <<= 1)
          #pragma unroll
          for (int i = 0; i < 16; i += 2 * st) v[i] += v[i + st];
        acc += v[0];
      }
      if (j + 8 <= je) {
        int s[8];
        #pragma unroll
        for (int i = 0; i < 8; ++i) s[i] = ep[j + i];
        float v[8];
        #pragma unroll
        for (int i = 0; i < 8; ++i) v[i] = bf2f(y[s[i] * 40 + lane]);
        acc += ((v[0] + v[1]) + (v[2] + v[3])) + ((v[4] + v[5]) + (v[6] + v[7]));
        j += 8;
      }
      if (j + 4 <= je) {
        int s0 = ep[j+0], s1 = ep[j+1], s2 = ep[j+2], s3 = ep[j+3];
        float v0 = bf2f(y[s0*40 + lane]);
        float v1 = bf2f(y[s1*40 + lane]);
        float v2 = bf2f(y[s2*40 + lane]);
        float v3 = bf2f(y[s3*40 + lane]);
        acc += (v0 + v1) + (v2 + v3);
        j += 4;
      }
      for (; j < je; ++j) acc += bf2f(y[ep[j] * 40 + lane]);
    }
    float v = (lane < 40) ? fmaf(acc, invd[node], yr[node * 40 + lane]) : -1e30f;
    float m = v;
    #pragma unroll
    for (int off = 32; off >= 1; off >>= 1) m = fmaxf(m, __shfl_xor(m, off, 64));
    float e_ = (lane < 40) ? __expf(v - m) : 0.f;
    float s_ = e_;
    #pragma unroll
    for (int off = 32; off >= 1; off >>= 1) s_ += __shfl_xor(s_, off, 64);
    if (lane < 40) out[node * 40 + lane] = v - m - __logf(s_);
  }
}

extern "C" void kernel_launch(void* const* d_in, const int* in_sizes, int n_in,
                              void* d_out, int out_size, void* d_ws, size_t ws_size,
                              hipStream_t stream) {
  const float* x   = (const float*)d_in[0];
  const int*   esrc = (const int*)d_in[1];
  const int*   edst = (const int*)d_in[2];
  const float* af  = (const float*)d_in[3];
  const float* Wl0 = (const float*)d_in[4];
  const float* Wr0 = (const float*)d_in[5];
  const float* b0  = (const float*)d_in[6];
  const float* g0  = (const float*)d_in[7];
  const float* be0 = (const float*)d_in[8];
  const float* Wl1 = (const float*)d_in[9];
  const float* Wr1 = (const float*)d_in[10];
  const float* b1  = (const float*)d_in[11];
  const float* g1  = (const float*)d_in[12];
  const float* be1 = (const float*)d_in[13];
  const float* Wf  = (const float*)d_in[14];
  const float* bfv = (const float*)d_in[15];
  const float* Wl2 = (const float*)d_in[16];
  const float* Wr2 = (const float*)d_in[17];
  const float* b2  = (const float*)d_in[18];

  float* ws   = (float*)d_ws;
  float* invd = ws;                          // N
  float* bufA = ws + (size_t)100000;         // N*64 region; bf16 msgs / bf16 yl (aliased)
  float* bufB = bufA + (size_t)6400000;      // N*64 (h_pre)
  float* bufC = bufB + (size_t)6400000;      // N*64 (yr stage; 40ch in final layer)
  float* stats = bufC + (size_t)6400000;     // 512 (layer0 raw @0, layer1 raw @128)
  float* Wcl  = stats + 512;                 // 40*128
  float* Wcr  = Wcl + 5120;                  // 40*128
  float* bc   = Wcr + 5120;                  // 80
  float* WT0  = bc + 80;                     // 128*128
  float* WT1  = WT0 + 16384;                 // 64*128
  float* WTF  = WT1 + 8192;                  // 192*80
  int*   counts = (int*)(WTF + 15360);       // N (aliased as cursor)
  int*   rowptr = counts + 100000;           // N+1
  int*   srcs   = rowptr + 100001;           // E
  int*   blk    = srcs + N_EDGES;            // SCAN_NBLK
  unsigned short* msg = (unsigned short*)bufA;  // N*64 bf16 (dead before final GEMM writes yl)
  unsigned short* ylb = (unsigned short*)bufA;  // N*40 bf16 (final layer)
  float* out  = (float*)d_out;

  // ---- CSR build (reused by all 3 layers) ----
  hipMemsetAsync(counts, 0, 100000*sizeof(int), stream);
  hipMemsetAsync(stats, 0, 512*sizeof(float), stream);
  k_count<<<6250, 256, 0, stream>>>(edst, counts);
  k_scan_a<<<SCAN_NBLK, 256, 0, stream>>>(counts, blk);
  k_scan_b<<<1, 128, 0, stream>>>(blk);
  k_scan_c<<<SCAN_NBLK, 256, 0, stream>>>(counts, blk, rowptr, counts /*cursor alias*/, invd);
  k_place<<<6250, 256, 0, stream>>>(esrc, edst, counts, srcs);

  k_precomp<<<40, 128, 0, stream>>>(Wl2, Wr2, Wf, bfv, b2, Wcl, Wcr, bc);
  k_buildwt<128><<<64, 256, 0, stream>>>(Wl0, Wr0, WT0);
  k_buildwt<64><<<32, 256, 0, stream>>>(Wl1, Wr1, WT1);
  k_buildwtf<<<60, 256, 0, stream>>>(Wl2, Wr2, Wcl, Wcr, WTF);

  // ---- layer 0 ----
  k_gemm_dual<128,false><<<3125, 256, 0, stream>>>(x, nullptr, nullptr, nullptr, WT0, b0, msg, bufC);
  k_gather64<true><<<6250, 256, 0, stream>>>(rowptr, srcs, msg, bufC, invd, bufB, stats);

  // ---- layer 1 (BN from layer-0 raw stats, fused) ----
  k_gemm_dual<64,true><<<3125, 256, 0, stream>>>(bufB, stats, g0, be0, WT1, b1, msg, bufC);
  k_gather64<true><<<6250, 256, 0, stream>>>(rowptr, srcs, msg, bufC, invd, bufB, stats + 128);

  // ---- final layer (BN from layer-1 raw stats, fused; concat folded; yl bf16) ----
  k_gemm_final<<<1563, 320, 0, stream>>>(bufB, stats + 128, g1, be1, af, WTF, bc, ylb, bufC);
  k_gather_out<<<6250, 256, 0, stream>>>(rowptr, srcs, ylb, bufC, invd, out);
}

// Round 12
// 683.707 us; speedup vs baseline: 1.3230x; 1.1112x over previous
//
#include <hip/hip_runtime.h>

#define N_NODES 100000
#define N_EDGES 1600000
#define SCAN_NBLK 98   // ceil(100000/1024)
#define SMAX 1024      // staged edges per block (16 nodes, mean 256)

typedef float4 f4;
typedef __attribute__((ext_vector_type(8))) short short8v;
typedef __attribute__((ext_vector_type(4))) float f32x4;

__device__ __forceinline__ float bf2f(unsigned short v) {
  return __uint_as_float(((unsigned)v) << 16);
}
__device__ __forceinline__ unsigned short f2bf(float f) {
  unsigned u = __float_as_uint(f);
  u += 0x7FFF + ((u >> 16) & 1);   // round-to-nearest-even
  return (unsigned short)(u >> 16);
}
__device__ __forceinline__ float bfLO(unsigned u) { return __uint_as_float(u << 16); }
__device__ __forceinline__ float bfHI(unsigned u) { return __uint_as_float(u & 0xFFFF0000u); }

// ---------------- CSR build ----------------
__global__ __launch_bounds__(256) void k_count(const int* __restrict__ dst, int* __restrict__ counts) {
  int i = blockIdx.x * 256 + threadIdx.x;
  if (i < N_EDGES) atomicAdd(&counts[dst[i]], 1);
}

__global__ __launch_bounds__(256) void k_scan_a(const int* __restrict__ counts, int* __restrict__ blk) {
  __shared__ int red[256];
  const int t = threadIdx.x;
  const int base = blockIdx.x * 1024;
  int s = 0;
  #pragma unroll
  for (int i = 0; i < 4; ++i) {
    int idx = base + t + i * 256;
    if (idx < N_NODES) s += counts[idx];
  }
  red[t] = s; __syncthreads();
  for (int off = 128; off >= 1; off >>= 1) {
    if (t < off) red[t] += red[t + off];
    __syncthreads();
  }
  if (t == 0) blk[blockIdx.x] = red[0];
}

__global__ __launch_bounds__(128) void k_scan_b(int* __restrict__ blk) {
  __shared__ int v[128];
  const int t = threadIdx.x;
  int val = (t < SCAN_NBLK) ? blk[t] : 0;
  v[t] = val; __syncthreads();
  for (int off = 1; off < 128; off <<= 1) {
    int a = (t >= off) ? v[t - off] : 0;
    __syncthreads();
    v[t] += a;
    __syncthreads();
  }
  if (t < SCAN_NBLK) blk[t] = v[t] - val;  // exclusive
}

__global__ __launch_bounds__(256) void k_scan_c(const int* __restrict__ counts, const int* __restrict__ blkoff,
                                                int* __restrict__ rowptr, int* __restrict__ cursor,
                                                float* __restrict__ invd) {
  __shared__ int ps[256];
  const int t = threadIdx.x;
  const int base = blockIdx.x * 1024 + t * 4;
  int c[4]; int s = 0;
  #pragma unroll
  for (int i = 0; i < 4; ++i) {
    int idx = base + i;
    c[i] = (idx < N_NODES) ? counts[idx] : 0;
    s += c[i];
  }
  ps[t] = s; __syncthreads();
  for (int off = 1; off < 256; off <<= 1) {
    int a = (t >= off) ? ps[t - off] : 0;
    __syncthreads();
    ps[t] += a;
    __syncthreads();
  }
  int run = blkoff[blockIdx.x] + ps[t] - s;
  #pragma unroll
  for (int i = 0; i < 4; ++i) {
    int idx = base + i;
    if (idx < N_NODES) {
      rowptr[idx] = run;
      cursor[idx] = run;
      invd[idx] = 1.0f / fmaxf((float)c[i], 1.0f);
      run += c[i];
      if (idx == N_NODES - 1) rowptr[N_NODES] = run;
    }
  }
}

__global__ __launch_bounds__(256) void k_place(const int* __restrict__ src, const int* __restrict__ dst,
                                               int* __restrict__ cursor, int* __restrict__ srcs) {
  int e = blockIdx.x * 256 + threadIdx.x;
  if (e < N_EDGES) {
    int pos = atomicAdd(&cursor[dst[e]], 1);
    srcs[pos] = src[e];
  }
}

// ------------- combined projection weights for final layer -------------
__global__ void k_precomp(const float* __restrict__ Wl2, const float* __restrict__ Wr2,
                          const float* __restrict__ Wf, const float* __restrict__ bfv,
                          const float* __restrict__ b2,
                          float* __restrict__ Wcl, float* __restrict__ Wcr, float* __restrict__ bc) {
  int o = blockIdx.x, k = threadIdx.x;  // o<40, k<128
  float al = 0.f, ar = 0.f;
  for (int j = 0; j < 64; ++j) {
    float wl = Wl2[o*128 + 64 + j], wr = Wr2[o*128 + 64 + j];
    float wf = Wf[j*128 + k];
    al = fmaf(wl, wf, al); ar = fmaf(wr, wf, ar);
  }
  Wcl[o*128 + k] = al; Wcr[o*128 + k] = ar;
  if (k == 0) {
    float sl = 0.f, sr = 0.f;
    for (int j = 0; j < 64; ++j) { sl += Wl2[o*128+64+j]*bfv[j]; sr += Wr2[o*128+64+j]*bfv[j]; }
    bc[o] = sl; bc[40+o] = sr + b2[o];
  }
}

// bf16 pre-swizzled B-blob [col][K]: elem idx ^= ((col&7)<<3)  (matches LDS read swizzle)
template<int K>
__global__ __launch_bounds__(256) void k_buildwt(const float* __restrict__ W1, const float* __restrict__ W2,
                                                 unsigned short* __restrict__ dst) {
  int idx = blockIdx.x * 256 + threadIdx.x;
  if (idx >= 128*K) return;
  int col = idx / K, k = idx - col*K;
  float w = (col < 64) ? W1[col*K + k] : W2[(col-64)*K + k];
  dst[idx ^ ((col & 7) << 3)] = f2bf(w);
}

// final blob: 3 k-chunks of [80 cols][64 k], each pre-swizzled
__global__ __launch_bounds__(256) void k_buildwtf(const float* __restrict__ Wl2, const float* __restrict__ Wr2,
                                                  const float* __restrict__ Wcl, const float* __restrict__ Wcr,
                                                  unsigned short* __restrict__ dst) {
  int idx = blockIdx.x * 256 + threadIdx.x;
  if (idx >= 80*192) return;
  int col = idx / 192, k = idx - col*192;
  float w;
  if (col < 40) w = (k < 64) ? Wl2[col*128 + k] : Wcl[col*128 + (k-64)];
  else { int c = col - 40; w = (k < 64) ? Wr2[c*128 + k] : Wcr[c*128 + (k-64)]; }
  int kc = k >> 6, kk = k & 63;
  dst[kc*(80*64) + (((col*64 + kk)) ^ ((col & 7) << 3))] = f2bf(w);
}

// ------------- MFMA dual GEMM: out1(bf16)=in@W1.T, out2(f32)=in@W2.T+bias2 -------------
// 64 rows/block, 4 waves x 16-row strips; A/B bf16 in LDS with ((row&7)<<3) elem-XOR swizzle.
// frag maps: A lane: row=l&15,k=(l>>4)*8+j ; B lane: col=l&15,k=(l>>4)*8+j ; C: col=l&15,row=(l>>4)*4+j
template<int K, bool BN>
__global__ __launch_bounds__(256) void k_gemm_dual(
    const float* __restrict__ in, const float* __restrict__ stats,
    const float* __restrict__ g, const float* __restrict__ be,
    const unsigned short* __restrict__ wtg, const float* __restrict__ bias2,
    unsigned short* __restrict__ out1, float* __restrict__ out2) {
  __shared__ unsigned short wsb[128*K];
  __shared__ unsigned short xsb[64*K];
  __shared__ float ssl[128];
  const int tx = threadIdx.x;
  if (BN) {
    if (tx < 64) {
      float mean = stats[tx] * (1.0f / N_NODES);
      float var  = stats[64+tx] * (1.0f / N_NODES) - mean*mean;
      float scale = g[tx] * rsqrtf(var + 1e-5f);
      ssl[tx] = scale; ssl[64+tx] = be[tx] - mean*scale;
    }
    __syncthreads();
  }
  const int row0 = blockIdx.x * 64;
  for (int i = tx; i < 128*K/8; i += 256)
    ((uint4*)wsb)[i] = ((const uint4*)wtg)[i];
  for (int i = tx; i < 64*(K/4); i += 256) {
    int row = i / (K/4), kq = i - row*(K/4);
    int grow = row0 + row;
    f4 v = {0.f,0.f,0.f,0.f};
    if (grow < N_NODES) {
      v = *(const f4*)&in[grow*K + kq*4];
      if (BN) {
        int c = kq*4;
        v.x = fmaxf(0.f, fmaf(v.x, ssl[c+0], ssl[64+c+0]));
        v.y = fmaxf(0.f, fmaf(v.y, ssl[c+1], ssl[64+c+1]));
        v.z = fmaxf(0.f, fmaf(v.z, ssl[c+2], ssl[64+c+2]));
        v.w = fmaxf(0.f, fmaf(v.w, ssl[c+3], ssl[64+c+3]));
      }
    }
    ushort4 o;
    o.x = f2bf(v.x); o.y = f2bf(v.y); o.z = f2bf(v.z); o.w = f2bf(v.w);
    *(ushort4*)&xsb[(row*K + kq*4) ^ ((row & 7) << 3)] = o;
  }
  __syncthreads();
  const int lane = tx & 63, wr = tx >> 6;
  const int rloc = lane & 15, kblk = lane >> 4;
  f32x4 acc[8];
  #pragma unroll
  for (int ct = 0; ct < 8; ++ct) acc[ct] = (f32x4){0.f,0.f,0.f,0.f};
  const int arow = wr*16 + rloc;
  #pragma unroll
  for (int ks = 0; ks < K/32; ++ks) {
    short8v a = *(short8v*)&xsb[(arow*K + ks*32 + kblk*8) ^ ((arow & 7) << 3)];
    #pragma unroll
    for (int ct = 0; ct < 8; ++ct) {
      int bcol = ct*16 + rloc;
      short8v b = *(short8v*)&wsb[(bcol*K + ks*32 + kblk*8) ^ ((bcol & 7) << 3)];
      acc[ct] = __builtin_amdgcn_mfma_f32_16x16x32_bf16(a, b, acc[ct], 0, 0, 0);
    }
  }
  const int crow0 = row0 + wr*16 + kblk*4;
  #pragma unroll
  for (int ct = 0; ct < 8; ++ct) {
    int gcol = ct*16 + rloc;
    if (gcol < 64) {
      #pragma unroll
      for (int j = 0; j < 4; ++j) {
        int grow = crow0 + j;
        if (grow < N_NODES) out1[grow*64 + gcol] = f2bf(acc[ct][j]);
      }
    } else {
      float bv = bias2[gcol - 64];
      #pragma unroll
      for (int j = 0; j < 4; ++j) {
        int grow = crow0 + j;
        if (grow < N_NODES) out2[grow*64 + (gcol-64)] = acc[ct][j] + bv;
      }
    }
  }
}

// ------------- MFMA final dual GEMM: 80 out cols, K=192 (64 BN(hpre) + 128 af), W chunked 3x64 ----
__global__ __launch_bounds__(256) void k_gemm_final(
    const float* __restrict__ hpre, const float* __restrict__ stats,
    const float* __restrict__ g, const float* __restrict__ be,
    const float* __restrict__ af, const unsigned short* __restrict__ wtg,
    const float* __restrict__ bc,
    unsigned short* __restrict__ yl, float* __restrict__ yr) {
  __shared__ unsigned short xsb[64*192];  // 24 KB
  __shared__ unsigned short wsb[80*64];   // 10 KB
  __shared__ float ssl[128];
  const int tx = threadIdx.x;
  if (tx < 64) {
    float mean = stats[tx] * (1.0f / N_NODES);
    float var  = stats[64+tx] * (1.0f / N_NODES) - mean*mean;
    float scale = g[tx] * rsqrtf(var + 1e-5f);
    ssl[tx] = scale; ssl[64+tx] = be[tx] - mean*scale;
  }
  __syncthreads();
  const int row0 = blockIdx.x * 64;
  for (int i = tx; i < 64*48; i += 256) {
    int row = i / 48, kq = i - row*48;
    int grow = row0 + row; int k0 = kq*4;
    f4 v = {0.f,0.f,0.f,0.f};
    if (grow < N_NODES) {
      if (k0 < 64) {
        v = *(const f4*)&hpre[grow*64 + k0];
        v.x = fmaxf(0.f, fmaf(v.x, ssl[k0+0], ssl[64+k0+0]));
        v.y = fmaxf(0.f, fmaf(v.y, ssl[k0+1], ssl[64+k0+1]));
        v.z = fmaxf(0.f, fmaf(v.z, ssl[k0+2], ssl[64+k0+2]));
        v.w = fmaxf(0.f, fmaf(v.w, ssl[k0+3], ssl[64+k0+3]));
      } else {
        v = *(const f4*)&af[grow*128 + (k0-64)];
      }
    }
    ushort4 o;
    o.x = f2bf(v.x); o.y = f2bf(v.y); o.z = f2bf(v.z); o.w = f2bf(v.w);
    *(ushort4*)&xsb[(row*192 + k0) ^ ((row & 7) << 3)] = o;
  }
  const int lane = tx & 63, wr = tx >> 6;
  const int rloc = lane & 15, kblk = lane >> 4;
  f32x4 acc[5];
  #pragma unroll
  for (int ct = 0; ct < 5; ++ct) acc[ct] = (f32x4){0.f,0.f,0.f,0.f};
  const int arow = wr*16 + rloc;
  for (int kc = 0; kc < 3; ++kc) {
    __syncthreads();   // xsb ready (kc=0) / previous chunk's reads done
    for (int i = tx; i < 80*64/8; i += 256)
      ((uint4*)wsb)[i] = ((const uint4*)(wtg + kc*80*64))[i];
    __syncthreads();
    #pragma unroll
    for (int ks = 0; ks < 2; ++ks) {
      int kg = kc*64 + ks*32;
      short8v a = *(short8v*)&xsb[(arow*192 + kg + kblk*8) ^ ((arow & 7) << 3)];
      #pragma unroll
      for (int ct = 0; ct < 5; ++ct) {
        int bcol = ct*16 + rloc;
        short8v b = *(short8v*)&wsb[(bcol*64 + ks*32 + kblk*8) ^ ((bcol & 7) << 3)];
        acc[ct] = __builtin_amdgcn_mfma_f32_16x16x32_bf16(a, b, acc[ct], 0, 0, 0);
      }
    }
  }
  const int crow0 = row0 + wr*16 + kblk*4;
  #pragma unroll
  for (int ct = 0; ct < 5; ++ct) {
    int gcol = ct*16 + rloc;
    float bv = bc[gcol];
    if (gcol < 40) {
      #pragma unroll
      for (int j = 0; j < 4; ++j) {
        int grow = crow0 + j;
        if (grow < N_NODES) yl[grow*40 + gcol] = f2bf(acc[ct][j] + bv);
      }
    } else {
      int cc = gcol - 40;
      #pragma unroll
      for (int j = 0; j < 4; ++j) {
        int grow = crow0 + j;
        if (grow < N_NODES) yr[grow*40 + cc] = acc[ct][j] + bv;
      }
    }
  }
}

// ------------- CSR gather (bf16 msgs), edge-parallel + LDS-staged indices -------------
template<bool STATS>
__global__ __launch_bounds__(256) void k_gather64(
    const int* __restrict__ rowptr, const int* __restrict__ srcs,
    const unsigned short* __restrict__ y, const float* __restrict__ yr,
    const float* __restrict__ invd, float* __restrict__ hpre, float* __restrict__ stats) {
  __shared__ float ssum[64], ssq[64];
  __shared__ int slds[SMAX];
  const int t = threadIdx.x;
  const int lane = t & 63, w = t >> 6;
  const int eg = lane >> 4;      // 0..3
  const int cl = lane & 15;      // 0..15
  const int nblk = blockIdx.x * 16;
  if (STATS && t < 64) { ssum[t] = 0.f; ssq[t] = 0.f; }
  const int boff = rowptr[nblk];
  const int tot  = rowptr[nblk + 16] - boff;
  const bool useLds = (tot <= SMAX);
  if (useLds) {
    for (int i = t; i < tot; i += 256) slds[i] = srcs[boff + i];
  }
  __syncthreads();
  const int* __restrict__ ep = useLds ? slds : srcs + boff;  // indices relative to boff
  const int node0 = nblk + w * 4;
  float ps0 = 0.f, ps1 = 0.f, ps2 = 0.f, ps3 = 0.f;
  float pq0 = 0.f, pq1 = 0.f, pq2 = 0.f, pq3 = 0.f;
  for (int n = 0; n < 4; ++n) {
    const int node = node0 + n;
    const int jb = rowptr[node] - boff, je = rowptr[node + 1] - boff;
    float a0 = 0.f, a1 = 0.f, a2 = 0.f, a3 = 0.f;
    int j = jb;
    for (; j + 16 <= je; j += 16) {
      int s0 = ep[j + eg];
      int s1 = ep[j + 4 + eg];
      int s2 = ep[j + 8 + eg];
      int s3 = ep[j + 12 + eg];
      uint2 va = *(const uint2*)&y[(size_t)s0 * 64 + (cl << 2)];
      uint2 vb = *(const uint2*)&y[(size_t)s1 * 64 + (cl << 2)];
      uint2 vc = *(const uint2*)&y[(size_t)s2 * 64 + (cl << 2)];
      uint2 vd = *(const uint2*)&y[(size_t)s3 * 64 + (cl << 2)];
      a0 += (bfLO(va.x) + bfLO(vb.x)) + (bfLO(vc.x) + bfLO(vd.x));
      a1 += (bfHI(va.x) + bfHI(vb.x)) + (bfHI(vc.x) + bfHI(vd.x));
      a2 += (bfLO(va.y) + bfLO(vb.y)) + (bfLO(vc.y) + bfLO(vd.y));
      a3 += (bfHI(va.y) + bfHI(vb.y)) + (bfHI(vc.y) + bfHI(vd.y));
    }
    for (; j + 4 <= je; j += 4) {
      int s0 = ep[j + eg];
      uint2 va = *(const uint2*)&y[(size_t)s0 * 64 + (cl << 2)];
      a0 += bfLO(va.x); a1 += bfHI(va.x); a2 += bfLO(va.y); a3 += bfHI(va.y);
    }
    {
      int rem = je - j;
      if (eg < rem) {
        int s0 = ep[j + eg];
        uint2 va = *(const uint2*)&y[(size_t)s0 * 64 + (cl << 2)];
        a0 += bfLO(va.x); a1 += bfHI(va.x); a2 += bfLO(va.y); a3 += bfHI(va.y);
      }
    }
    // fold the 4 edge groups (lane bits 4,5)
    a0 += __shfl_xor(a0, 16, 64); a1 += __shfl_xor(a1, 16, 64);
    a2 += __shfl_xor(a2, 16, 64); a3 += __shfl_xor(a3, 16, 64);
    a0 += __shfl_xor(a0, 32, 64); a1 += __shfl_xor(a1, 32, 64);
    a2 += __shfl_xor(a2, 32, 64); a3 += __shfl_xor(a3, 32, 64);
    if (eg == 0) {
      float inv = invd[node];
      f4 yv = *(const f4*)&yr[(size_t)node * 64 + (cl << 2)];
      f4 h;
      h.x = fmaf(a0, inv, yv.x); h.y = fmaf(a1, inv, yv.y);
      h.z = fmaf(a2, inv, yv.z); h.w = fmaf(a3, inv, yv.w);
      *(f4*)&hpre[(size_t)node * 64 + (cl << 2)] = h;
      if (STATS) {
        ps0 += h.x; ps1 += h.y; ps2 += h.z; ps3 += h.w;
        pq0 += h.x*h.x; pq1 += h.y*h.y; pq2 += h.z*h.z; pq3 += h.w*h.w;
      }
    }
  }
  if (STATS) {
    if (eg == 0) {
      atomicAdd(&ssum[(cl<<2)+0], ps0); atomicAdd(&ssum[(cl<<2)+1], ps1);
      atomicAdd(&ssum[(cl<<2)+2], ps2); atomicAdd(&ssum[(cl<<2)+3], ps3);
      atomicAdd(&ssq[(cl<<2)+0], pq0); atomicAdd(&ssq[(cl<<2)+1], pq1);
      atomicAdd(&ssq[(cl<<2)+2], pq2); atomicAdd(&ssq[(cl<<2)+3], pq3);
    }
    __syncthreads();
    if (t < 64) { atomicAdd(&stats[t], ssum[t]); atomicAdd(&stats[64 + t], ssq[t]); }
  }
}

// ------------- CSR gather (40ch bf16) + log_softmax, LDS-staged indices -------------
__global__ __launch_bounds__(256) void k_gather_out(
    const int* __restrict__ rowptr, const int* __restrict__ srcs,
    const unsigned short* __restrict__ y, const float* __restrict__ yr,
    const float* __restrict__ invd, float* __restrict__ out) {
  __shared__ int slds[SMAX];
  const int t = threadIdx.x;
  const int lane = t & 63, w = t >> 6;
  const int nblk = blockIdx.x * 16;
  const int boff = rowptr[nblk];
  const int tot  = rowptr[nblk + 16] - boff;
  const bool useLds = (tot <= SMAX);
  if (useLds) {
    for (int i = t; i < tot; i += 256) slds[i] = srcs[boff + i];
  }
  __syncthreads();
  const int* __restrict__ ep = useLds ? slds : srcs + boff;
  const int node0 = nblk + w * 4;
  #pragma unroll
  for (int n = 0; n < 4; ++n) {
    const int node = node0 + n;
    const int jb = rowptr[node] - boff, je = rowptr[node + 1] - boff;
    float acc = 0.f;
    if (lane < 40) {
      int j = jb;
      for (; j + 16 <= je; j += 16) {
        int s[16];
        #pragma unroll
        for (int i = 0; i < 16; ++i) s[i] = ep[j + i];
        float v[16];
        #pragma unroll
        for (int i = 0; i < 16; ++i) v[i] = bf2f(y[s[i] * 40 + lane]);
        #pragma unroll
        for (int st = 1; st < 16; st <<= 1)
          #pragma unroll
          for (int i = 0; i < 16; i += 2 * st) v[i] += v[i + st];
        acc += v[0];
      }
      if (j + 8 <= je) {
        int s[8];
        #pragma unroll
        for (int i = 0; i < 8; ++i) s[i] = ep[j + i];
        float v[8];
        #pragma unroll
        for (int i = 0; i < 8; ++i) v[i] = bf2f(y[s[i] * 40 + lane]);
        acc += ((v[0] + v[1]) + (v[2] + v[3])) + ((v[4] + v[5]) + (v[6] + v[7]));
        j += 8;
      }
      if (j + 4 <= je) {
        int s0 = ep[j+0], s1 = ep[j+1], s2 = ep[j+2], s3 = ep[j+3];
        float v0 = bf2f(y[s0*40 + lane]);
        float v1 = bf2f(y[s1*40 + lane]);
        float v2 = bf2f(y[s2*40 + lane]);
        float v3 = bf2f(y[s3*40 + lane]);
        acc += (v0 + v1) + (v2 + v3);
        j += 4;
      }
      for (; j < je; ++j) acc += bf2f(y[ep[j] * 40 + lane]);
    }
    float v = (lane < 40) ? fmaf(acc, invd[node], yr[node * 40 + lane]) : -1e30f;
    float m = v;
    #pragma unroll
    for (int off = 32; off >= 1; off >>= 1) m = fmaxf(m, __shfl_xor(m, off, 64));
    float e_ = (lane < 40) ? __expf(v - m) : 0.f;
    float s_ = e_;
    #pragma unroll
    for (int off = 32; off >= 1; off >>= 1) s_ += __shfl_xor(s_, off, 64);
    if (lane < 40) out[node * 40 + lane] = v - m - __logf(s_);
  }
}

extern "C" void kernel_launch(void* const* d_in, const int* in_sizes, int n_in,
                              void* d_out, int out_size, void* d_ws, size_t ws_size,
                              hipStream_t stream) {
  const float* x   = (const float*)d_in[0];
  const int*   esrc = (const int*)d_in[1];
  const int*   edst = (const int*)d_in[2];
  const float* af  = (const float*)d_in[3];
  const float* Wl0 = (const float*)d_in[4];
  const float* Wr0 = (const float*)d_in[5];
  const float* b0  = (const float*)d_in[6];
  const float* g0  = (const float*)d_in[7];
  const float* be0 = (const float*)d_in[8];
  const float* Wl1 = (const float*)d_in[9];
  const float* Wr1 = (const float*)d_in[10];
  const float* b1  = (const float*)d_in[11];
  const float* g1  = (const float*)d_in[12];
  const float* be1 = (const float*)d_in[13];
  const float* Wf  = (const float*)d_in[14];
  const float* bfv = (const float*)d_in[15];
  const float* Wl2 = (const float*)d_in[16];
  const float* Wr2 = (const float*)d_in[17];
  const float* b2  = (const float*)d_in[18];

  float* ws   = (float*)d_ws;
  float* invd = ws;                          // N
  float* bufA = ws + (size_t)100000;         // N*64 region; bf16 msgs / bf16 yl (aliased)
  float* bufB = bufA + (size_t)6400000;      // N*64 (h_pre)
  float* bufC = bufB + (size_t)6400000;      // N*64 (yr stage; 40ch in final layer)
  float* stats = bufC + (size_t)6400000;     // 512 (layer0 raw @0, layer1 raw @128)
  float* Wcl  = stats + 512;                 // 40*128
  float* Wcr  = Wcl + 5120;                  // 40*128
  float* bc   = Wcr + 5120;                  // 80
  float* WT0f = bc + 80;                     // slot: 16384 floats (blob uses 16384 ushorts)
  float* WT1f = WT0f + 16384;                // slot: 8192 floats
  float* WTFf = WT1f + 8192;                 // slot: 15360 floats
  int*   counts = (int*)(WTFf + 15360);      // N (aliased as cursor)
  int*   rowptr = counts + 100000;           // N+1
  int*   srcs   = rowptr + 100001;           // E
  int*   blk    = srcs + N_EDGES;            // SCAN_NBLK
  unsigned short* WT0 = (unsigned short*)WT0f;  // [128 col][128 k] bf16, pre-swizzled
  unsigned short* WT1 = (unsigned short*)WT1f;  // [128 col][64 k]
  unsigned short* WTF = (unsigned short*)WTFf;  // 3 chunks [80 col][64 k]
  unsigned short* msg = (unsigned short*)bufA;  // N*64 bf16 (dead before final GEMM writes yl)
  unsigned short* ylb = (unsigned short*)bufA;  // N*40 bf16 (final layer)
  float* out  = (float*)d_out;

  // ---- CSR build (reused by all 3 layers) ----
  hipMemsetAsync(counts, 0, 100000*sizeof(int), stream);
  hipMemsetAsync(stats, 0, 512*sizeof(float), stream);
  k_count<<<6250, 256, 0, stream>>>(edst, counts);
  k_scan_a<<<SCAN_NBLK, 256, 0, stream>>>(counts, blk);
  k_scan_b<<<1, 128, 0, stream>>>(blk);
  k_scan_c<<<SCAN_NBLK, 256, 0, stream>>>(counts, blk, rowptr, counts /*cursor alias*/, invd);
  k_place<<<6250, 256, 0, stream>>>(esrc, edst, counts, srcs);

  k_precomp<<<40, 128, 0, stream>>>(Wl2, Wr2, Wf, bfv, b2, Wcl, Wcr, bc);
  k_buildwt<128><<<64, 256, 0, stream>>>(Wl0, Wr0, WT0);
  k_buildwt<64><<<32, 256, 0, stream>>>(Wl1, Wr1, WT1);
  k_buildwtf<<<60, 256, 0, stream>>>(Wl2, Wr2, Wcl, Wcr, WTF);

  // ---- layer 0 (MFMA GEMM) ----
  k_gemm_dual<128,false><<<1563, 256, 0, stream>>>(x, nullptr, nullptr, nullptr, WT0, b0, msg, bufC);
  k_gather64<true><<<6250, 256, 0, stream>>>(rowptr, srcs, msg, bufC, invd, bufB, stats);

  // ---- layer 1 (BN fused from layer-0 raw stats; MFMA GEMM) ----
  k_gemm_dual<64,true><<<1563, 256, 0, stream>>>(bufB, stats, g0, be0, WT1, b1, msg, bufC);
  k_gather64<true><<<6250, 256, 0, stream>>>(rowptr, srcs, msg, bufC, invd, bufB, stats + 128);

  // ---- final layer (BN fused; concat folded; MFMA GEMM; yl bf16) ----
  k_gemm_final<<<1563, 256, 0, stream>>>(bufB, stats + 128, g1, be1, af, WTF, bc, ylb, bufC);
  k_gather_out<<<6250, 256, 0, stream>>>(rowptr, srcs, ylb, bufC, invd, out);
}